// Round 12
// baseline (208.844 us; speedup 1.0000x reference)
//
#include <hip/hip_runtime.h>
#include <hip/hip_bf16.h>

// MatchingLayer: out[b,i,j] = <l2norm(a[b,i,:]*w), l2norm(b[b,j,:]*w)>
// B=16, L=1024, D=1024.
//  K1 (R12): asm-load norm — 8 inline-asm global_load_dwordx4 with "=v"
//      outputs force 8 distinct VGPR quads in flight (regalloc cannot
//      re-serialize). 1 row-pair/wave, 16384 waves, manual vmcnt(0) +
//      sched_barrier (rule #18). Math path identical to R10 (verified).
//  K2: batched bf16 GEMM, 256x256 tile, BK=64, 8 waves, 8-phase schedule
//      (T2 swizzle + T3/T4 counted vmcnt + T5 setprio), fp32 out. (frozen,
//      R3-verified)

typedef __bf16 bf16x8 __attribute__((ext_vector_type(8)));
typedef float f32x4 __attribute__((ext_vector_type(4)));

__device__ __forceinline__ unsigned short f2bf(float f) {
  __hip_bfloat16 h = __float2bfloat16(f);
  return *reinterpret_cast<unsigned short*>(&h);
}

__device__ __forceinline__ ushort4 pack4(float4 v, float s) {
  ushort4 u;
  u.x = f2bf(v.x * s); u.y = f2bf(v.y * s);
  u.z = f2bf(v.z * s); u.w = f2bf(v.w * s);
  return u;
}

// opaque 16B load: output is a distinct live VGPR quad; compiler cannot
// serialize/recycle these registers or reorder the issue.
__device__ __forceinline__ float4 aload16(const float* p) {
  float4 r;
  asm volatile("global_load_dwordx4 %0, %1, off" : "=v"(r) : "v"(p));
  return r;
}

__device__ __forceinline__ void gload16(const void* g, void* ldsp) {
  __builtin_amdgcn_global_load_lds(
      (const __attribute__((address_space(1))) unsigned int*)g,
      (__attribute__((address_space(3))) unsigned int*)ldsp,
      16, 0, 0);
}

// ---------------- Kernel 1: row l2-normalize of x*w, output bf16 ----------
// 4096 blocks x 256 thr; wave wid handles a-row wid AND b-row wid.
// Lane owns elems {c*256 + lane*4 .. +3}, c=0..3.
__global__ void __launch_bounds__(256)
norm_scale_kernel(const float* __restrict__ a, const float* __restrict__ b,
                  const float* __restrict__ w, unsigned short* __restrict__ ra,
                  unsigned short* __restrict__ rb) {
  const int wave = threadIdx.x >> 6;
  const int lane = threadIdx.x & 63;
  const int wid = blockIdx.x * 4 + wave;  // 0..16383
  const size_t rowoff = (size_t)wid * 1024;
  const int e = lane * 4;

  const float* pa = a + rowoff + e;
  const float* pb = b + rowoff + e;

  // 8 forced-in-flight HBM loads (asm) + 4 L2-broadcast w loads
  float4 xa0 = aload16(pa);
  float4 xa1 = aload16(pa + 256);
  float4 xa2 = aload16(pa + 512);
  float4 xa3 = aload16(pa + 768);
  float4 xb0 = aload16(pb);
  float4 xb1 = aload16(pb + 256);
  float4 xb2 = aload16(pb + 512);
  float4 xb3 = aload16(pb + 768);
  float4 w0 = *(const float4*)(w + e);
  float4 w1 = *(const float4*)(w + 256 + e);
  float4 w2 = *(const float4*)(w + 512 + e);
  float4 w3 = *(const float4*)(w + 768 + e);

  asm volatile("s_waitcnt vmcnt(0)" ::: "memory");
  __builtin_amdgcn_sched_barrier(0);  // rule #18: pin consumers below wait

  xa0.x *= w0.x; xa0.y *= w0.y; xa0.z *= w0.z; xa0.w *= w0.w;
  xa1.x *= w1.x; xa1.y *= w1.y; xa1.z *= w1.z; xa1.w *= w1.w;
  xa2.x *= w2.x; xa2.y *= w2.y; xa2.z *= w2.z; xa2.w *= w2.w;
  xa3.x *= w3.x; xa3.y *= w3.y; xa3.z *= w3.z; xa3.w *= w3.w;
  xb0.x *= w0.x; xb0.y *= w0.y; xb0.z *= w0.z; xb0.w *= w0.w;
  xb1.x *= w1.x; xb1.y *= w1.y; xb1.z *= w1.z; xb1.w *= w1.w;
  xb2.x *= w2.x; xb2.y *= w2.y; xb2.z *= w2.z; xb2.w *= w2.w;
  xb3.x *= w3.x; xb3.y *= w3.y; xb3.z *= w3.z; xb3.w *= w3.w;

  float sa = xa0.x * xa0.x + xa0.y * xa0.y + xa0.z * xa0.z + xa0.w * xa0.w;
  sa += xa1.x * xa1.x + xa1.y * xa1.y + xa1.z * xa1.z + xa1.w * xa1.w;
  sa += xa2.x * xa2.x + xa2.y * xa2.y + xa2.z * xa2.z + xa2.w * xa2.w;
  sa += xa3.x * xa3.x + xa3.y * xa3.y + xa3.z * xa3.z + xa3.w * xa3.w;
  float sb = xb0.x * xb0.x + xb0.y * xb0.y + xb0.z * xb0.z + xb0.w * xb0.w;
  sb += xb1.x * xb1.x + xb1.y * xb1.y + xb1.z * xb1.z + xb1.w * xb1.w;
  sb += xb2.x * xb2.x + xb2.y * xb2.y + xb2.z * xb2.z + xb2.w * xb2.w;
  sb += xb3.x * xb3.x + xb3.y * xb3.y + xb3.z * xb3.z + xb3.w * xb3.w;

#pragma unroll
  for (int off = 32; off > 0; off >>= 1) {
    sa += __shfl_xor(sa, off);
    sb += __shfl_xor(sb, off);
  }
  const float fa = rsqrtf(fmaxf(sa, 1e-12f));
  const float fb = rsqrtf(fmaxf(sb, 1e-12f));

  *(ushort4*)(ra + rowoff + e) = pack4(xa0, fa);
  *(ushort4*)(ra + rowoff + 256 + e) = pack4(xa1, fa);
  *(ushort4*)(ra + rowoff + 512 + e) = pack4(xa2, fa);
  *(ushort4*)(ra + rowoff + 768 + e) = pack4(xa3, fa);
  *(ushort4*)(rb + rowoff + e) = pack4(xb0, fb);
  *(ushort4*)(rb + rowoff + 256 + e) = pack4(xb1, fb);
  *(ushort4*)(rb + rowoff + 512 + e) = pack4(xb2, fb);
  *(ushort4*)(rb + rowoff + 768 + e) = pack4(xb3, fb);
}

// ---------------- Kernel 2: 256x256 8-phase batched GEMM ------------------
// LDS per buffer: A 256x64 bf16 (32KB) + B 256x64 (32KB); 2 buffers = 128KB.
// A half h holds global tile-rows via grow = ((rr>>6)<<7) + h*64 + (rr&63),
// rr = row within half.  B half h: grow = ((rr>>5)<<6) + h*32 + (rr&31).
// Swizzle: 16B chunk position = chunk ^ (row&7); applied on global src
// (stage) and on ds_read addr; LDS dest of global_load_lds stays linear.
__global__ void __launch_bounds__(512, 2)
gemm8_kernel(const unsigned short* __restrict__ RA,
             const unsigned short* __restrict__ RB,
             float* __restrict__ C) {
  __shared__ __align__(16) char lds[131072];

  const int t = threadIdx.x;
  const int w = t >> 6, l = t & 63;
  const int wr = w >> 2, wc = w & 3;    // 2 x 4 wave grid
  const int l4 = l & 15, lh = l >> 4;
  const int lr = l >> 3;                // staging row-within-8 = swizzle key
  const int lch = (l & 7) ^ lr;         // staged global 16B-chunk index

  // bijective XCD swizzle (256 WGs, 256%8==0)
  const int orig = (int)blockIdx.x;
  const int wgid = (orig & 7) * 32 + (orig >> 3);
  const int batch = wgid >> 4;
  const int tile = wgid & 15;
  const int brow_t = (tile >> 2) << 8;
  const int bcol_t = (tile & 3) << 8;

  const unsigned short* Ab = RA + ((size_t)batch << 20) + (size_t)brow_t * 1024;
  const unsigned short* Bb = RB + ((size_t)batch << 20) + (size_t)bcol_t * 1024;

  int aoff[2][2], boff[2][2];
#pragma unroll
  for (int h = 0; h < 2; ++h)
#pragma unroll
    for (int g = 0; g < 2; ++g) {
      const int rr = w * 16 + g * 8 + lr;                 // row within half
      const int ga = ((rr >> 6) << 7) + h * 64 + (rr & 63);
      const int gb = ((rr >> 5) << 6) + h * 32 + (rr & 31);
      aoff[h][g] = ga * 1024 + lch * 8;
      boff[h][g] = gb * 1024 + lch * 8;
    }
  const int stgw = w * 2048;

  // fragment-read addressing (region-relative bytes)
  const int arow = (wr * 64 + l4) * 128;
  const int brow = (wc * 32 + l4) * 128;
  int csw[2];
  csw[0] = ((0 + lh) ^ (l & 7)) * 16;
  csw[1] = ((4 + lh) ^ (l & 7)) * 16;

  f32x4 acc[8][4] = {};
  bf16x8 af[4][2], bq0[2][2], bq1[2][2];

#define STAGE_A(h, tau)                                                   \
  do {                                                                    \
    char* _d = lds + ((tau) & 1) * 65536 + (h) * 16384 + stgw;            \
    gload16(Ab + (size_t)aoff[h][0] + (size_t)(tau) * 64, _d);            \
    gload16(Ab + (size_t)aoff[h][1] + (size_t)(tau) * 64, _d + 1024);     \
  } while (0)
#define STAGE_B(h, tau)                                                   \
  do {                                                                    \
    char* _d = lds + ((tau) & 1) * 65536 + 32768 + (h) * 16384 + stgw;    \
    gload16(Bb + (size_t)boff[h][0] + (size_t)(tau) * 64, _d);            \
    gload16(Bb + (size_t)boff[h][1] + (size_t)(tau) * 64, _d + 1024);     \
  } while (0)
#define LDA(mh, bufbase)                                                  \
  _Pragma("unroll") for (int mm = 0; mm < 4; ++mm)                        \
  _Pragma("unroll") for (int ks = 0; ks < 2; ++ks)                        \
      af[mm][ks] = *(const bf16x8*)((bufbase) + (mh) * 16384 + arow +     \
                                    mm * 2048 + csw[ks]);
#define LDB(dst, nh, bufbase)                                             \
  _Pragma("unroll") for (int nn = 0; nn < 2; ++nn)                        \
  _Pragma("unroll") for (int ks = 0; ks < 2; ++ks)                        \
      dst[nn][ks] = *(const bf16x8*)((bufbase) + 32768 + (nh) * 16384 +   \
                                     brow + nn * 2048 + csw[ks]);
#define MQ(mh, nh, bsrc)                                                  \
  _Pragma("unroll") for (int mm = 0; mm < 4; ++mm)                        \
  _Pragma("unroll") for (int nn = 0; nn < 2; ++nn)                        \
  _Pragma("unroll") for (int ks = 0; ks < 2; ++ks)                        \
      acc[(mh) * 4 + mm][(nh) * 2 + nn] =                                 \
          __builtin_amdgcn_mfma_f32_16x16x32_bf16(                        \
              af[mm][ks], bsrc[nn][ks], acc[(mh) * 4 + mm][(nh) * 2 + nn],\
              0, 0, 0);
#define PHASE_PRE()                                                       \
  __builtin_amdgcn_s_barrier();                                           \
  asm volatile("s_waitcnt lgkmcnt(0)" ::: "memory");                      \
  __builtin_amdgcn_sched_barrier(0);                                      \
  __builtin_amdgcn_s_setprio(1)
#define PHASE_POST()                                                      \
  __builtin_amdgcn_s_setprio(0);                                          \
  __builtin_amdgcn_s_barrier()

  const char* b0 = lds;
  const char* b1 = lds + 65536;

  // prologue: tile0 fully, tile1 3/4 staged; wait tile0 (14 issued -> 6 left)
  STAGE_A(0, 0); STAGE_B(0, 0); STAGE_B(1, 0); STAGE_A(1, 0);
  STAGE_A(0, 1); STAGE_B(0, 1); STAGE_B(1, 1);
  asm volatile("s_waitcnt vmcnt(6)" ::: "memory");
  __builtin_amdgcn_s_barrier();

#pragma unroll 1
  for (int i = 0; i < 7; ++i) {
    const int u = 2 * i;
    // p1: q00(u); stage Ah1(u+1) [completes tile u+1]
    LDA(0, b0); LDB(bq0, 0, b0); STAGE_A(1, u + 1);
    PHASE_PRE(); MQ(0, 0, bq0); PHASE_POST();
    // p2: q01(u); stage Ah0(u+2) (Ah0(u) died @p1)
    LDB(bq1, 1, b0); STAGE_A(0, u + 2);
    PHASE_PRE(); MQ(0, 1, bq1); PHASE_POST();
    // p3: q11(u); stage Bh0(u+2) (Bh0(u) died @p1)
    LDA(1, b0); STAGE_B(0, u + 2);
    PHASE_PRE(); MQ(1, 1, bq1); PHASE_POST();
    // p4: q10(u); stage Bh1(u+2) (died @p2); checkpoint covers tile u+1
    STAGE_B(1, u + 2);
    asm volatile("s_waitcnt vmcnt(6)" ::: "memory");
    PHASE_PRE(); MQ(1, 0, bq0); PHASE_POST();
    // p5: q00(u+1); stage Ah1(u+2) (Ah1(u) died @p3)
    LDA(0, b1); LDB(bq0, 0, b1); STAGE_A(1, u + 2);
    PHASE_PRE(); MQ(0, 0, bq0); PHASE_POST();
    // p6: q01(u+1); stage Ah0(u+3)
    LDB(bq1, 1, b1); STAGE_A(0, u + 3);
    PHASE_PRE(); MQ(0, 1, bq1); PHASE_POST();
    // p7: q11(u+1); stage Bh0(u+3)
    LDA(1, b1); STAGE_B(0, u + 3);
    PHASE_PRE(); MQ(1, 1, bq1); PHASE_POST();
    // p8: q10(u+1); stage Bh1(u+3); checkpoint covers tile u+2
    STAGE_B(1, u + 3);
    asm volatile("s_waitcnt vmcnt(6)" ::: "memory");
    PHASE_PRE(); MQ(1, 0, bq0); PHASE_POST();
  }

  // peeled final iteration: u=14, v=15 (no out-of-range stages)
  LDA(0, b0); LDB(bq0, 0, b0); STAGE_A(1, 15);
  PHASE_PRE(); MQ(0, 0, bq0); PHASE_POST();
  LDB(bq1, 1, b0);
  PHASE_PRE(); MQ(0, 1, bq1); PHASE_POST();
  LDA(1, b0);
  PHASE_PRE(); MQ(1, 1, bq1); PHASE_POST();
  asm volatile("s_waitcnt vmcnt(0)" ::: "memory");
  PHASE_PRE(); MQ(1, 0, bq0); PHASE_POST();
  LDA(0, b1); LDB(bq0, 0, b1);
  PHASE_PRE(); MQ(0, 0, bq0); PHASE_POST();
  LDB(bq1, 1, b1);
  PHASE_PRE(); MQ(0, 1, bq1); PHASE_POST();
  LDA(1, b1);
  PHASE_PRE(); MQ(1, 1, bq1); PHASE_POST();
  PHASE_PRE(); MQ(1, 0, bq0); PHASE_POST();

#undef STAGE_A
#undef STAGE_B
#undef LDA
#undef LDB
#undef MQ
#undef PHASE_PRE
#undef PHASE_POST

  // epilogue: C/D layout col=lane&15, row=(lane>>4)*4+reg
  float* Cb = C + ((size_t)batch << 20);
  const int crow0 = brow_t + wr * 128 + lh * 4;
  const int ccol0 = bcol_t + wc * 64 + l4;
#pragma unroll
  for (int m = 0; m < 8; ++m)
#pragma unroll
    for (int n = 0; n < 4; ++n)
#pragma unroll
      for (int r = 0; r < 4; ++r)
        Cb[(size_t)(crow0 + m * 16 + r) * 1024 + ccol0 + n * 16] =
            acc[m][n][r];
}

extern "C" void kernel_launch(void* const* d_in, const int* in_sizes, int n_in,
                              void* d_out, int out_size, void* d_ws, size_t ws_size,
                              hipStream_t stream) {
  const float* a = (const float*)d_in[0];
  const float* b = (const float*)d_in[1];
  const float* w = (const float*)d_in[2];
  float* out = (float*)d_out;

  unsigned short* ra = (unsigned short*)d_ws;                 // 16M bf16
  unsigned short* rb = ra + (size_t)16 * 1024 * 1024;         // 16M bf16

  norm_scale_kernel<<<4096, 256, 0, stream>>>(a, b, w, ra, rb);
  gemm8_kernel<<<256, 512, 0, stream>>>(ra, rb, out);
}

// Round 13
// 199.394 us; speedup vs baseline: 1.0474x; 1.0474x over previous
//
#include <hip/hip_runtime.h>
#include <hip/hip_bf16.h>

// MatchingLayer fused: out[b,i,j] = <a_i*w, b_j*w> * rsqrt(|a_i*w|^2) * rsqrt(|b_j*w|^2)
// B=16, L=1024, D=1024.  SINGLE kernel (R13):
//  - 256 WGs (16 batches x 16 tiles), 512 thr, 256x256 tile, BK=64, 16 K-tiles
//  - reg-staged: f32 global loads -> *w -> bf16 -> ds_write (same swizzled
//    LDS layout as the R3-verified gload_lds path; fragment reads unchanged)
//  - per-row sumsq accumulated during staging; octet shfl-reduce; epilogue
//    scales C by fa*fb  (normalization commutes with the dot product)
//  - double-buffered LDS, ONE barrier per K-tile, T5 setprio on MFMA clusters

typedef __bf16 bf16x8 __attribute__((ext_vector_type(8)));
typedef float f32x4 __attribute__((ext_vector_type(4)));
typedef unsigned short us8 __attribute__((ext_vector_type(8)));

__device__ __forceinline__ unsigned short f2bf(float f) {
  __hip_bfloat16 h = __float2bfloat16(f);
  return *reinterpret_cast<unsigned short*>(&h);
}

__global__ void __launch_bounds__(512, 2)
fused_kernel(const float* __restrict__ A, const float* __restrict__ Bm,
             const float* __restrict__ W, float* __restrict__ C) {
  __shared__ __align__(16) char lds[131072];   // 2 buf x (A 32KB | B 32KB)
  __shared__ __align__(16) float wlds[1024];   // w
  __shared__ float nAl[256], nBl[256];         // rsqrt norms per tile row/col

  const int t = threadIdx.x;
  const int w = t >> 6, l = t & 63;
  const int wr = w >> 2, wc = w & 3;   // 2 x 4 wave grid
  const int l4 = l & 15, lh = l >> 4;
  const int lr = l >> 3;               // octet id within wave
  const int lch = (l & 7) ^ lr;        // swizzled global 16B-chunk index

  // bijective XCD swizzle (256 WGs, 256%8==0)
  const int orig = (int)blockIdx.x;
  const int wgid = (orig & 7) * 32 + (orig >> 3);
  const int batch = wgid >> 4;
  const int tile = wgid & 15;
  const int brow_t = (tile >> 2) << 8;
  const int bcol_t = (tile & 3) << 8;

  const float* Af = A + ((size_t)batch << 20) + (size_t)brow_t * 1024;
  const float* Bf = Bm + ((size_t)batch << 20) + (size_t)bcol_t * 1024;

  int aoffs[2][2], boffs[2][2], garow[2][2], gbrow[2][2];
#pragma unroll
  for (int h = 0; h < 2; ++h)
#pragma unroll
    for (int g = 0; g < 2; ++g) {
      const int rr = w * 16 + g * 8 + lr;               // row within half
      const int ga = ((rr >> 6) << 7) + h * 64 + (rr & 63);
      const int gb = ((rr >> 5) << 6) + h * 32 + (rr & 31);
      garow[h][g] = ga; gbrow[h][g] = gb;
      aoffs[h][g] = ga * 1024 + lch * 8;                // f32 elem offsets
      boffs[h][g] = gb * 1024 + lch * 8;
    }
  const int stgw = w * 2048;

  // fragment-read addressing (unchanged from verified R3 path)
  const int arow = (wr * 64 + l4) * 128;
  const int brow = (wc * 32 + l4) * 128;
  int csw[2];
  csw[0] = ((0 + lh) ^ (l & 7)) * 16;
  csw[1] = ((4 + lh) ^ (l & 7)) * 16;

  f32x4 acc[8][4] = {};
  bf16x8 af[4][2], bq[2][2];
  float nsq[8] = {0.f, 0.f, 0.f, 0.f, 0.f, 0.f, 0.f, 0.f};
  float4 xv[2][2];   // in-flight staging loads (one half at a time)
  float4 ws0, ws1;   // w slice for this thread's k-chunk

  // stage w -> LDS once
  if (t < 256) ((float4*)wlds)[t] = ((const float4*)W)[t];
  __syncthreads();

#define ALOAD(h, t1)                                                      \
  _Pragma("unroll") for (int g = 0; g < 2; ++g) {                         \
    const float* _p = Af + aoffs[h][g] + (t1) * 64;                       \
    xv[g][0] = *(const float4*)_p;                                        \
    xv[g][1] = *(const float4*)(_p + 4);                                  \
  }
#define BLOAD(h, t1)                                                      \
  _Pragma("unroll") for (int g = 0; g < 2; ++g) {                         \
    const float* _p = Bf + boffs[h][g] + (t1) * 64;                       \
    xv[g][0] = *(const float4*)_p;                                        \
    xv[g][1] = *(const float4*)(_p + 4);                                  \
  }
#define WSLICE(t1)                                                        \
  ws0 = *(const float4*)(wlds + (t1) * 64 + lch * 8);                     \
  ws1 = *(const float4*)(wlds + (t1) * 64 + lch * 8 + 4);
#define CVTW(isB, h, nxtbase)                                             \
  _Pragma("unroll") for (int g = 0; g < 2; ++g) {                         \
    float4 v0, v1;                                                        \
    v0.x = xv[g][0].x * ws0.x; v0.y = xv[g][0].y * ws0.y;                 \
    v0.z = xv[g][0].z * ws0.z; v0.w = xv[g][0].w * ws0.w;                 \
    v1.x = xv[g][1].x * ws1.x; v1.y = xv[g][1].y * ws1.y;                 \
    v1.z = xv[g][1].z * ws1.z; v1.w = xv[g][1].w * ws1.w;                 \
    nsq[(isB) * 4 + (h) * 2 + g] +=                                       \
        v0.x * v0.x + v0.y * v0.y + v0.z * v0.z + v0.w * v0.w +           \
        v1.x * v1.x + v1.y * v1.y + v1.z * v1.z + v1.w * v1.w;            \
    us8 pk;                                                               \
    pk[0] = f2bf(v0.x); pk[1] = f2bf(v0.y);                               \
    pk[2] = f2bf(v0.z); pk[3] = f2bf(v0.w);                               \
    pk[4] = f2bf(v1.x); pk[5] = f2bf(v1.y);                               \
    pk[6] = f2bf(v1.z); pk[7] = f2bf(v1.w);                               \
    *(us8*)((nxtbase) + (isB) * 32768 + (h) * 16384 + stgw + g * 1024 +   \
            l * 16) = pk;                                                 \
  }
#define LDAF(mh, bufb)                                                    \
  _Pragma("unroll") for (int mm = 0; mm < 4; ++mm)                        \
  _Pragma("unroll") for (int ks = 0; ks < 2; ++ks)                        \
      af[mm][ks] = *(const bf16x8*)((bufb) + (mh) * 16384 + arow +        \
                                    mm * 2048 + csw[ks]);
#define LDBQ(nh, bufb)                                                    \
  _Pragma("unroll") for (int nn = 0; nn < 2; ++nn)                        \
  _Pragma("unroll") for (int ks = 0; ks < 2; ++ks)                        \
      bq[nn][ks] = *(const bf16x8*)((bufb) + 32768 + (nh) * 16384 +       \
                                    brow + nn * 2048 + csw[ks]);
#define MQ(mh, nh)                                                        \
  __builtin_amdgcn_s_setprio(1);                                          \
  _Pragma("unroll") for (int mm = 0; mm < 4; ++mm)                        \
  _Pragma("unroll") for (int nn = 0; nn < 2; ++nn)                        \
  _Pragma("unroll") for (int ks = 0; ks < 2; ++ks)                        \
      acc[(mh) * 4 + mm][(nh) * 2 + nn] =                                 \
          __builtin_amdgcn_mfma_f32_16x16x32_bf16(                        \
              af[mm][ks], bq[nn][ks], acc[(mh) * 4 + mm][(nh) * 2 + nn],  \
              0, 0, 0);                                                   \
  __builtin_amdgcn_s_setprio(0);

  char* b0p = lds;
  char* b1p = lds + 65536;

  // prologue: stage tile 0 into buf0
  WSLICE(0);
  ALOAD(0, 0); CVTW(0, 0, b0p);
  ALOAD(1, 0); CVTW(0, 1, b0p);
  BLOAD(0, 0); CVTW(1, 0, b0p);
  BLOAD(1, 0); CVTW(1, 1, b0p);
  __syncthreads();

#pragma unroll 1
  for (int kt = 0; kt < 15; ++kt) {
    char* cur = (kt & 1) ? b1p : b0p;
    char* nxt = (kt & 1) ? b0p : b1p;
    WSLICE(kt + 1);
    // -- A-half0 compute; stage A(t+1) --
    ALOAD(0, kt + 1);
    LDBQ(0, cur); LDAF(0, cur);
    MQ(0, 0);
    CVTW(0, 0, nxt);
    ALOAD(1, kt + 1);
    LDBQ(1, cur);
    MQ(0, 1);
    CVTW(0, 1, nxt);
    // -- A-half1 compute; stage B(t+1) --
    BLOAD(0, kt + 1);
    LDAF(1, cur); LDBQ(0, cur);
    MQ(1, 0);
    CVTW(1, 0, nxt);
    BLOAD(1, kt + 1);
    LDBQ(1, cur);
    MQ(1, 1);
    CVTW(1, 1, nxt);
    __syncthreads();   // nxt fully written; everyone done reading cur
  }
  {  // tail: tile 15 in b1p, no staging
    char* cur = b1p;
    LDBQ(0, cur); LDAF(0, cur); MQ(0, 0);
    LDBQ(1, cur); MQ(0, 1);
    LDAF(1, cur); LDBQ(0, cur); MQ(1, 0);
    LDBQ(1, cur); MQ(1, 1);
  }

#undef ALOAD
#undef BLOAD
#undef WSLICE
#undef CVTW
#undef LDAF
#undef LDBQ
#undef MQ

  // ---- norm reduction: row partials live in one 8-lane octet ----
#pragma unroll
  for (int i = 0; i < 8; ++i) {
    nsq[i] += __shfl_xor(nsq[i], 1);
    nsq[i] += __shfl_xor(nsq[i], 2);
    nsq[i] += __shfl_xor(nsq[i], 4);
  }
  if ((l & 7) == 0) {
#pragma unroll
    for (int h = 0; h < 2; ++h)
#pragma unroll
      for (int g = 0; g < 2; ++g) {
        nAl[garow[h][g]] = rsqrtf(fmaxf(nsq[h * 2 + g], 1e-12f));
        nBl[gbrow[h][g]] = rsqrtf(fmaxf(nsq[4 + h * 2 + g], 1e-12f));
      }
  }
  __syncthreads();

  // ---- epilogue: C = acc * fa * fb  (C/D: col=lane&15, row=(lane>>4)*4+reg)
  float* Cb = C + ((size_t)batch << 20);
  const int crow0 = brow_t + wr * 128 + lh * 4;
  const int ccol0 = bcol_t + wc * 64 + l4;
  float fbv[4];
#pragma unroll
  for (int n = 0; n < 4; ++n) fbv[n] = nBl[wc * 64 + l4 + n * 16];
#pragma unroll
  for (int m = 0; m < 8; ++m)
#pragma unroll
    for (int r = 0; r < 4; ++r) {
      const float fav = nAl[wr * 128 + lh * 4 + m * 16 + r];
#pragma unroll
      for (int n = 0; n < 4; ++n)
        Cb[(size_t)(crow0 + m * 16 + r) * 1024 + ccol0 + n * 16] =
            acc[m][n][r] * fav * fbv[n];
    }
}

extern "C" void kernel_launch(void* const* d_in, const int* in_sizes, int n_in,
                              void* d_out, int out_size, void* d_ws, size_t ws_size,
                              hipStream_t stream) {
  const float* a = (const float*)d_in[0];
  const float* b = (const float*)d_in[1];
  const float* w = (const float*)d_in[2];
  float* out = (float*)d_out;

  fused_kernel<<<256, 512, 0, stream>>>(a, b, w, out);
}